// Round 12
// baseline (3321.742 us; speedup 1.0000x reference)
//
#include <hip/hip_runtime.h>

#define NN 25000
#define NP 25088   // NN padded to multiple of 128
#define FD 128
#define SD 256
#define LD 64
#define NE 400000
#define ROUNDS 4
#define CAP 96     // bucket capacity per dest (Poisson(16); P(deg>96)~1e-50)
#define MEGA_BLKS 1024   // 4 blocks/CU x 256 CU -> all co-resident (barrier-safe)

typedef __bf16 bf16;
typedef __bf16 bf16x4 __attribute__((ext_vector_type(4)));
typedef __bf16 bf16x8 __attribute__((ext_vector_type(8)));
typedef float  f32x4  __attribute__((ext_vector_type(4)));

// async global->LDS, 16B per lane; LDS dest = wave-uniform base + lane*16
#define GL16(g, l) __builtin_amdgcn_global_load_lds(                      \
    (const __attribute__((address_space(1))) void*)(g),                   \
    (__attribute__((address_space(3))) void*)(l), 16, 0, 0)

// ---------------------------------------------------------------------------
// Single-buffer bf16 MFMA GEMM body (round-11 proven): gload_lds + XOR
// swizzle, one 32KB-max LDS buffer.  A: bf16 [>=grid*128][K_].  Bt: [NTOT][K_].
// ---------------------------------------------------------------------------
template<int K_, int NTOT, int BN, int WM, int WN, int BIAS, int WF32, int WBF>
__device__ __forceinline__ void gemm1_body(
    const bf16* __restrict__ A, const bf16* __restrict__ Bt,
    const float* __restrict__ bias, float* __restrict__ C,
    bf16* __restrict__ Cb, int M, int bx, int by, char* lds)
{
    constexpr int BM = 128, BK = 64;
    constexpr int NT = K_ / BK;
    constexpr int FM = BM / WM / 16;
    constexpr int FN = BN / WN / 16;
    constexpr int ABYTES = BM * BK * 2;      // 16 KB
    constexpr int BCHW = (BN / 8) / 4;

    const int tid  = threadIdx.x;
    const int lane = tid & 63;
    const int w    = tid >> 6;
    const int wy   = w / WN;
    const int wx   = w % WN;
    const int m0   = by * BM;
    const int n0   = bx * BN;

    const int l8 = lane >> 3;
    const int bs = 16 * ((lane & 7) ^ l8);

    const char* Abase = (const char*)(A + (size_t)m0 * K_);
    const char* Bbase = (const char*)(Bt + (size_t)n0 * K_);
    char* dA = lds;
    char* dB = lds + ABYTES;

    f32x4 acc[FM][FN] = {};

    for (int t = 0; t < NT; ++t) {
        const int k0 = t * BK;
        #pragma unroll
        for (int i = 0; i < 4; ++i) {
            int c = w * 4 + i;
            GL16(Abase + (size_t)(c * 8 + l8) * (K_ * 2) + k0 * 2 + bs,
                 dA + c * 1024);
        }
        #pragma unroll
        for (int i = 0; i < BCHW; ++i) {
            int c = w * BCHW + i;
            GL16(Bbase + (size_t)(c * 8 + l8) * (K_ * 2) + k0 * 2 + bs,
                 dB + c * 1024);
        }
        __syncthreads();     // compiler drains vmcnt before barrier

        #pragma unroll
        for (int ks = 0; ks < 2; ++ks) {
            const int kk2 = ks * 64 + (lane >> 4) * 16;
            bf16x8 af[FM], bfr[FN];
            #pragma unroll
            for (int r = 0; r < FM; ++r) {
                int m = wy * (FM * 16) + r * 16 + (lane & 15);
                af[r] = *(const bf16x8*)(dA + m * 128 + (kk2 ^ ((m & 7) << 4)));
            }
            #pragma unroll
            for (int cI = 0; cI < FN; ++cI) {
                int n = wx * (FN * 16) + cI * 16 + (lane & 15);
                bfr[cI] = *(const bf16x8*)(dB + n * 128 + (kk2 ^ ((n & 7) << 4)));
            }
            #pragma unroll
            for (int r = 0; r < FM; ++r)
                #pragma unroll
                for (int cI = 0; cI < FN; ++cI)
                    acc[r][cI] = __builtin_amdgcn_mfma_f32_16x16x32_bf16(
                        af[r], bfr[cI], acc[r][cI], 0, 0, 0);
        }
        __syncthreads();     // protect buffer before next stage
    }

    #pragma unroll
    for (int r = 0; r < FM; ++r) {
        #pragma unroll
        for (int j = 0; j < 4; ++j) {
            int m = m0 + wy * (FM * 16) + r * 16 + (lane >> 4) * 4 + j;
            if (m >= M) continue;
            #pragma unroll
            for (int cI = 0; cI < FN; ++cI) {
                int n = n0 + wx * (FN * 16) + cI * 16 + (lane & 15);
                float v = acc[r][cI][j];
                if (BIAS) v += bias[n];
                if (WF32) C[(size_t)m * NTOT + n] = v;
                if (WBF)  Cb[(size_t)m * NTOT + n] = (bf16)v;
            }
        }
    }
}

// ---------------------------------------------------------------------------
// Double-buffer gemm body (round-6 proven) — used only inside prep (input GEMM
// uses its own inline fp32 staging; this is not referenced elsewhere).
// ---------------------------------------------------------------------------

// ---------------------------------------------------------------------------
// DIY grid barrier: monotonic counter, agent-scope atomics, fences both sides.
// SAFE only because all MEGA_BLKS blocks are co-resident (launch_bounds(256,4),
// 32KB LDS -> 4 blocks/CU x 256 CU = 1024 = grid size).
// ---------------------------------------------------------------------------
__device__ __forceinline__ void gbar(int* c, int target)
{
    __threadfence();                     // release: flush this block's stores
    __syncthreads();
    if (threadIdx.x == 0) {
        __hip_atomic_fetch_add(c, 1, __ATOMIC_ACQ_REL, __HIP_MEMORY_SCOPE_AGENT);
        while (__hip_atomic_load(c, __ATOMIC_ACQUIRE,
                                 __HIP_MEMORY_SCOPE_AGENT) < target)
            __builtin_amdgcn_s_sleep(1);
    }
    __syncthreads();
    __threadfence();                     // acquire: discard stale cache
}

// ---------------------------------------------------------------------------
// Mega kernel: ROUNDS x { msg GEMM phase | barrier | gather phase | barrier }
// then output GEMM.  Phase bodies identical to round-11 kernels.
// ---------------------------------------------------------------------------
__global__ __launch_bounds__(256, 4) void mega_kernel(
    bf16* __restrict__ sb, bf16* __restrict__ PQb,
    const bf16* __restrict__ Wb, const bf16* __restrict__ Wot,
    const float* __restrict__ b_msg, const float* __restrict__ b_out,
    float* __restrict__ out, const int* __restrict__ cnt,
    const int* __restrict__ bucket, int* __restrict__ gc)
{
    __shared__ char lds[32 * 1024];
    const int nb = gridDim.x;            // MEGA_BLKS
    const int w  = threadIdx.x >> 6;
    const int t  = threadIdx.x & 63;
    const int h  = t >> 5;
    const int lc = t & 31;
    int ph = 0;

    for (int r = 0; r < ROUNDS; ++r) {
        // ---- msg GEMM phase: PQ = sb @ [W1|W2], 784 tiles ----
        const bf16* Br = Wb + (size_t)r * 2 * SD * SD;
        if (blockIdx.x < 4 * (NP / 128))
            gemm1_body<SD, 512, 128, 2, 2, 0, 0, 1>(
                sb, Br, nullptr, nullptr, PQb, NP,
                blockIdx.x & 3, blockIdx.x >> 2, lds);
        ++ph; gbar(gc, ph * nb);

        // ---- gather phase: one node per wave, strided sweep ----
        const float* bias = b_msg + (size_t)r * SD;
        for (int d = blockIdx.x * 4 + w; d < NN; d += nb * 4) {
            int deg = min(cnt[d], CAP);
            if (deg == 0) continue;
            const int* row = bucket + (size_t)d * CAP;

            bf16x8 qv = *(const bf16x8*)&PQb[(size_t)d * 512 + 256 + lc * 8];
            float4 b0 = *(const float4*)&bias[lc * 8];
            float4 b1 = *(const float4*)&bias[lc * 8 + 4];
            float qb[8] = { (float)qv[0] + b0.x, (float)qv[1] + b0.y,
                            (float)qv[2] + b0.z, (float)qv[3] + b0.w,
                            (float)qv[4] + b1.x, (float)qv[5] + b1.y,
                            (float)qv[6] + b1.z, (float)qv[7] + b1.w };
            float s[8] = {};

            for (int c = 0; c < deg; c += 64) {
                int rem = min(64, deg - c);
                int et = (t < rem) ? row[c + t] : 0;
                int pairs = (rem + 1) >> 1;
                #pragma unroll 2
                for (int i = 0; i < pairs; ++i) {
                    int idx = 2 * i + h;
                    int sn = __shfl(et, idx);
                    if (idx < rem) {
                        bf16x8 p = *(const bf16x8*)&PQb[(size_t)sn * 512 + lc * 8];
                        #pragma unroll
                        for (int j = 0; j < 8; ++j)
                            s[j] += fmaxf((float)p[j] + qb[j], 0.f);
                    }
                }
            }

            #pragma unroll
            for (int j = 0; j < 8; ++j) s[j] += __shfl_xor(s[j], 32);

            if (h == 0) {
                size_t o = (size_t)d * SD + lc * 8;
                bf16x8 old = *(const bf16x8*)&sb[o];
                bf16x8 nv;
                #pragma unroll
                for (int j = 0; j < 8; ++j) nv[j] = (bf16)((float)old[j] + s[j]);
                *(bf16x8*)&sb[o] = nv;
            }
        }
        ++ph; gbar(gc, ph * nb);
    }

    // ---- output GEMM: out = sb @ W_out + b_out, 196 tiles ----
    if (blockIdx.x < NP / 128)
        gemm1_body<SD, LD, 64, 4, 1, 1, 1, 0>(
            sb, Wot, b_out, out, nullptr, NN, 0, blockIdx.x, lds);
}

// ---------------------------------------------------------------------------
// Fused prep: [input GEMM (inline fp32 staging)] + [LDS-tiled coalesced
// transposes of W_msg, W_out] + [bucket-append edge grouping].
// ---------------------------------------------------------------------------
#define GIN_BLK  (2 * (NP / 128))            // 392
#define TMSG_BLK (ROUNDS * 32)               // 128
#define TOUT_BLK 4
#define APP_BLK  ((NE + 255) / 256)          // 1563
#define PREP_BLKS (GIN_BLK + TMSG_BLK + TOUT_BLK + APP_BLK)

__global__ __launch_bounds__(256) void prep_fused(
    const float* __restrict__ x, const float* __restrict__ W_in,
    const float* __restrict__ W_msg, const float* __restrict__ W_out,
    const float* __restrict__ b_in,
    const int* __restrict__ src, const int* __restrict__ dest,
    bf16* __restrict__ sb, bf16* __restrict__ Wb, bf16* __restrict__ Wot,
    int* __restrict__ cnt, int* __restrict__ bucket)
{
    __shared__ union {
        struct { bf16 As[128][72]; bf16 Bs[128][72]; } g;   // 36.9 KB
        float tr[64][68];                                    // 17.4 KB
    } sm;

    const int bid = blockIdx.x;
    const int tid = threadIdx.x;

    if (bid < GIN_BLK) {
        const int lane = tid & 63, w = tid >> 6;
        const int wy = w >> 1, wx = w & 1;
        const int bx = bid & 1, by = bid >> 1;
        const int m0 = by * 128, n0 = bx * 128;
        f32x4 acc[4][4] = {};

        for (int k0 = 0; k0 < FD; k0 += 64) {
            #pragma unroll
            for (int i = 0; i < 8; ++i) {            // A: x fp32 -> bf16 LDS
                int c = i * 256 + tid;
                int row = c >> 4, off = (c & 15) * 4;
                int gr = m0 + row;
                float4 v = (gr < NN)
                    ? *(const float4*)&x[(size_t)gr * FD + k0 + off]
                    : make_float4(0.f, 0.f, 0.f, 0.f);
                bf16x4 o = { (bf16)v.x, (bf16)v.y, (bf16)v.z, (bf16)v.w };
                *(bf16x4*)&sm.g.As[row][off] = o;
            }
            #pragma unroll
            for (int ps = 0; ps < 8; ++ps) {         // B: W_in [k][n] -> Bs[n][k]
                int kr = ps * 8 + (tid >> 5);
                int nof = (tid & 31) * 4;
                float4 v = *(const float4*)&W_in[(size_t)(k0 + kr) * SD + n0 + nof];
                sm.g.Bs[nof + 0][kr] = (bf16)v.x;
                sm.g.Bs[nof + 1][kr] = (bf16)v.y;
                sm.g.Bs[nof + 2][kr] = (bf16)v.z;
                sm.g.Bs[nof + 3][kr] = (bf16)v.w;
            }
            __syncthreads();
            #pragma unroll
            for (int ks = 0; ks < 2; ++ks) {
                const int kk = ks * 32 + (lane >> 4) * 8;
                bf16x8 af[4], bfr[4];
                #pragma unroll
                for (int r = 0; r < 4; ++r)
                    af[r] = *(const bf16x8*)&sm.g.As[wy * 64 + r * 16 + (lane & 15)][kk];
                #pragma unroll
                for (int cI = 0; cI < 4; ++cI)
                    bfr[cI] = *(const bf16x8*)&sm.g.Bs[wx * 64 + cI * 16 + (lane & 15)][kk];
                #pragma unroll
                for (int r = 0; r < 4; ++r)
                    #pragma unroll
                    for (int cI = 0; cI < 4; ++cI)
                        acc[r][cI] = __builtin_amdgcn_mfma_f32_16x16x32_bf16(
                            af[r], bfr[cI], acc[r][cI], 0, 0, 0);
            }
            __syncthreads();
        }
        #pragma unroll
        for (int r = 0; r < 4; ++r)
            #pragma unroll
            for (int j = 0; j < 4; ++j) {
                int m = m0 + wy * 64 + r * 16 + (lane >> 4) * 4 + j;
                #pragma unroll
                for (int cI = 0; cI < 4; ++cI) {
                    int n = n0 + wx * 64 + cI * 16 + (lane & 15);
                    float v = fmaxf(acc[r][cI][j] + b_in[n], 0.f);
                    sb[(size_t)m * SD + n] = (bf16)v;
                }
            }
        return;
    }

    int tb = bid - GIN_BLK;
    if (tb < TMSG_BLK + TOUT_BLK) {
        // ---- 64x64 LDS-tiled transpose, fp32 -> bf16 ----
        const float* srcp; bf16* dstp; int sld, dld;
        if (tb < TMSG_BLK) {
            int r = tb >> 5, t5 = tb & 31, kt = t5 >> 2, nt = t5 & 3;
            int half = kt >> 2;
            srcp = W_msg + (size_t)r * 2 * SD * SD + (kt * 64) * SD + nt * 64;
            sld  = SD;
            dstp = Wb + (size_t)r * 2 * SD * SD
                      + (size_t)(half * 256 + nt * 64) * SD + (kt & 3) * 64;
            dld  = SD;
        } else {
            int kt = tb - TMSG_BLK;
            srcp = W_out + (size_t)kt * 64 * LD;
            sld  = LD;
            dstp = Wot + kt * 64;
            dld  = SD;
        }
        #pragma unroll
        for (int ps = 0; ps < 4; ++ps) {
            int row = ps * 16 + (tid >> 4), c0 = (tid & 15) * 4;
            float4 v = *(const float4*)&srcp[(size_t)row * sld + c0];
            sm.tr[row][c0 + 0] = v.x; sm.tr[row][c0 + 1] = v.y;
            sm.tr[row][c0 + 2] = v.z; sm.tr[row][c0 + 3] = v.w;
        }
        __syncthreads();
        #pragma unroll
        for (int ps = 0; ps < 4; ++ps) {
            int j = ps * 16 + (tid >> 4), i0 = (tid & 15) * 4;
            bf16x4 o = { (bf16)sm.tr[i0 + 0][j], (bf16)sm.tr[i0 + 1][j],
                         (bf16)sm.tr[i0 + 2][j], (bf16)sm.tr[i0 + 3][j] };
            *(bf16x4*)&dstp[(size_t)j * dld + i0] = o;
        }
        return;
    }

    // ---- bucket-append edge grouping ----
    int e = (tb - TMSG_BLK - TOUT_BLK) * 256 + tid;
    if (e < NE) {
        int d = dest[e];
        int pos = atomicAdd(&cnt[d], 1);
        if (pos < CAP) bucket[(size_t)d * CAP + pos] = src[e];
    }
}

// ---------------------------------------------------------------------------
// Zero kernel: per-dest counters + grid-barrier counter (NN + 16 ints)
// ---------------------------------------------------------------------------
__global__ __launch_bounds__(256) void zero_cnt(int* __restrict__ cnt)
{
    int i = blockIdx.x * 256 + threadIdx.x;
    if (i < NN + 16) cnt[i] = 0;
}

extern "C" void kernel_launch(void* const* d_in, const int* in_sizes, int n_in,
                              void* d_out, int out_size, void* d_ws, size_t ws_size,
                              hipStream_t stream)
{
    const float* x      = (const float*)d_in[0];
    const int*   eidx   = (const int*)d_in[1];
    const float* W_in   = (const float*)d_in[3];
    const float* b_in   = (const float*)d_in[4];
    const float* W_msg  = (const float*)d_in[5];
    const float* b_msg  = (const float*)d_in[6];
    const float* W_out  = (const float*)d_in[7];
    const float* b_out  = (const float*)d_in[8];
    float* out = (float*)d_out;

    const int* src  = eidx;
    const int* dest = eidx + NE;

    // ---- workspace layout (~50 MB) ----
    char* p = (char*)d_ws;
    bf16*  sb    = (bf16*)p;            p += (size_t)NP * SD * 2;
    bf16*  PQb   = (bf16*)p;            p += (size_t)NP * 512 * 2;
    bf16*  Wb    = (bf16*)p;            p += (size_t)ROUNDS * 2 * SD * SD * 2;
    bf16*  Wot   = (bf16*)p;            p += (size_t)LD * SD * 2;
    int*   cnt   = (int*)p;             p += (size_t)NN * 4;
    int*   gc    = (int*)p;             p += 16 * 4;      // grid-barrier counter
    int*   bucket= (int*)p;             p += (size_t)NN * CAP * 4;

    dim3 blk(256);

    // 1. zero per-dest counters + barrier counter
    zero_cnt<<<dim3((NN + 16 + 255) / 256), blk, 0, stream>>>(cnt);

    // 2. fused prep: input GEMM + weight transposes + bucket append
    prep_fused<<<dim3(PREP_BLKS), blk, 0, stream>>>(
        x, W_in, W_msg, W_out, b_in, src, dest, sb, Wb, Wot, cnt, bucket);

    // 3. mega kernel: all rounds + output GEMM, DIY grid barriers
    mega_kernel<<<dim3(MEGA_BLKS), blk, 0, stream>>>(
        sb, PQb, Wb, Wot, b_msg, b_out, out, cnt, bucket, gc);
}

// Round 13
// 226.099 us; speedup vs baseline: 14.6915x; 14.6915x over previous
//
#include <hip/hip_runtime.h>

#define NN 25000
#define NP 25088   // NN padded to multiple of 128
#define FD 128
#define SD 256
#define LD 64
#define NE 400000
#define ROUNDS 4
#define CAP 96     // bucket capacity per dest (Poisson(16); P(deg>96)~1e-50)

typedef __bf16 bf16;
typedef __bf16 bf16x4 __attribute__((ext_vector_type(4)));
typedef __bf16 bf16x8 __attribute__((ext_vector_type(8)));
typedef float  f32x4  __attribute__((ext_vector_type(4)));

// async global->LDS, 16B per lane; LDS dest = wave-uniform base + lane*16
#define GL16(g, l) __builtin_amdgcn_global_load_lds(                      \
    (const __attribute__((address_space(1))) void*)(g),                   \
    (__attribute__((address_space(3))) void*)(l), 16, 0, 0)

// ---------------------------------------------------------------------------
// bf16 MFMA GEMM body (round-6 proven, 4-wave): gload_lds + XOR swizzle +
// 2-phase double buffer.  Used by out_gemm.
// ---------------------------------------------------------------------------
template<int K_, int NTOT, int BN, int WM, int WN, int RELU, int BIAS,
         int WF32, int WBF>
__device__ __forceinline__ void gemm_body(
    const bf16* __restrict__ A, const bf16* __restrict__ Bt,
    const float* __restrict__ bias, float* __restrict__ C,
    bf16* __restrict__ Cb, int M, int bx, int by, char* lds)
{
    constexpr int BM = 128, BK = 64;
    constexpr int NT = K_ / BK;
    constexpr int FM = BM / WM / 16;
    constexpr int FN = BN / WN / 16;
    constexpr int ABYTES = BM * BK * 2;
    constexpr int BBYTES = BN * BK * 2;
    constexpr int BUF = ABYTES + BBYTES;
    constexpr int BCHW = (BN / 8) / 4;

    const int tid  = threadIdx.x;
    const int lane = tid & 63;
    const int w    = tid >> 6;
    const int wy   = w / WN;
    const int wx   = w % WN;
    const int m0   = by * BM;
    const int n0   = bx * BN;

    const int l8 = lane >> 3;
    const int bs = 16 * ((lane & 7) ^ l8);

    const char* Abase = (const char*)(A + (size_t)m0 * K_);
    const char* Bbase = (const char*)(Bt + (size_t)n0 * K_);

    f32x4 acc[FM][FN] = {};

#define STAGE(bufi, k0) do {                                              \
    char* dA = lds + (bufi) * BUF;                                        \
    char* dB = dA + ABYTES;                                               \
    _Pragma("unroll")                                                     \
    for (int i = 0; i < 4; ++i) {                                         \
        int c = w * 4 + i;                                                \
        GL16(Abase + (size_t)(c * 8 + l8) * (K_ * 2) + (k0) * 2 + bs,     \
             dA + c * 1024);                                              \
    }                                                                     \
    _Pragma("unroll")                                                     \
    for (int i = 0; i < BCHW; ++i) {                                      \
        int c = w * BCHW + i;                                             \
        GL16(Bbase + (size_t)(c * 8 + l8) * (K_ * 2) + (k0) * 2 + bs,     \
             dB + c * 1024);                                              \
    } } while (0)

    STAGE(0, 0);
    __syncthreads();

    for (int t = 0; t < NT; ++t) {
        if (t + 1 < NT) STAGE((t + 1) & 1, (t + 1) * BK);
        const char* Ab = lds + (t & 1) * BUF;
        const char* Bb = Ab + ABYTES;
        #pragma unroll
        for (int ks = 0; ks < 2; ++ks) {
            const int kk2 = ks * 64 + (lane >> 4) * 16;
            bf16x8 af[FM], bfr[FN];
            #pragma unroll
            for (int r = 0; r < FM; ++r) {
                int m = wy * (FM * 16) + r * 16 + (lane & 15);
                af[r] = *(const bf16x8*)(Ab + m * 128 + (kk2 ^ ((m & 7) << 4)));
            }
            #pragma unroll
            for (int cI = 0; cI < FN; ++cI) {
                int n = wx * (FN * 16) + cI * 16 + (lane & 15);
                bfr[cI] = *(const bf16x8*)(Bb + n * 128 + (kk2 ^ ((n & 7) << 4)));
            }
            #pragma unroll
            for (int r = 0; r < FM; ++r)
                #pragma unroll
                for (int cI = 0; cI < FN; ++cI)
                    acc[r][cI] = __builtin_amdgcn_mfma_f32_16x16x32_bf16(
                        af[r], bfr[cI], acc[r][cI], 0, 0, 0);
        }
        __syncthreads();
    }
#undef STAGE

    #pragma unroll
    for (int r = 0; r < FM; ++r) {
        #pragma unroll
        for (int j = 0; j < 4; ++j) {
            int m = m0 + wy * (FM * 16) + r * 16 + (lane >> 4) * 4 + j;
            if (m >= M) continue;
            #pragma unroll
            for (int cI = 0; cI < FN; ++cI) {
                int n = n0 + wx * (FN * 16) + cI * 16 + (lane & 15);
                float v = acc[r][cI][j];
                if (BIAS) v += bias[n];
                if (RELU) v = fmaxf(v, 0.f);
                if (WF32) C[(size_t)m * NTOT + n] = v;
                if (WBF)  Cb[(size_t)m * NTOT + n] = (bf16)v;
            }
        }
    }
}

// ---------------------------------------------------------------------------
// Msg GEMM: single-buffer, BN=256 wide tile, 8 waves (512 threads).
// A-panel re-read drops 4x -> 2x (BN 128->256 halves column-tiles).
// Grid 2 x 196 = 392 blocks at 2 blocks/CU -> one occupancy wave.
// Same gload_lds + XOR swizzle addressing as gemm_body.
// ---------------------------------------------------------------------------
__global__ __launch_bounds__(512, 4) void msg_gemm_kernel(
    const bf16* __restrict__ A, const bf16* __restrict__ Bt,
    bf16* __restrict__ Cb)
{
    constexpr int K_ = SD, BN = 256;
    constexpr int BM = 128, BK = 64;
    constexpr int NT = K_ / BK;          // 4
    constexpr int FM = 4, FN = 4;        // each wave: 64x64 output
    constexpr int ABYTES = BM * BK * 2;  // 16 KB
    __shared__ char lds[48 * 1024];      // A 16KB + B 32KB

    const int tid  = threadIdx.x;
    const int lane = tid & 63;
    const int w    = tid >> 6;           // 0..7
    const int wy   = w >> 2;             // 0..1  (2 wave-rows)
    const int wx   = w & 3;              // 0..3  (4 wave-cols)
    const int m0   = blockIdx.y * BM;
    const int n0   = blockIdx.x * BN;

    const int l8 = lane >> 3;
    const int bs = 16 * ((lane & 7) ^ l8);

    const char* Abase = (const char*)(A + (size_t)m0 * K_);
    const char* Bbase = (const char*)(Bt + (size_t)n0 * K_);
    char* dA = lds;
    char* dB = lds + ABYTES;

    f32x4 acc[FM][FN] = {};

    for (int t = 0; t < NT; ++t) {
        const int k0 = t * BK;
        #pragma unroll
        for (int i = 0; i < 2; ++i) {                // A: 16 chunks / 8 waves
            int c = w * 2 + i;
            GL16(Abase + (size_t)(c * 8 + l8) * (K_ * 2) + k0 * 2 + bs,
                 dA + c * 1024);
        }
        #pragma unroll
        for (int i = 0; i < 4; ++i) {                // B: 32 chunks / 8 waves
            int c = w * 4 + i;
            GL16(Bbase + (size_t)(c * 8 + l8) * (K_ * 2) + k0 * 2 + bs,
                 dB + c * 1024);
        }
        __syncthreads();     // compiler drains vmcnt before barrier

        #pragma unroll
        for (int ks = 0; ks < 2; ++ks) {
            const int kk2 = ks * 64 + (lane >> 4) * 16;
            bf16x8 af[FM], bfr[FN];
            #pragma unroll
            for (int r = 0; r < FM; ++r) {
                int m = wy * 64 + r * 16 + (lane & 15);
                af[r] = *(const bf16x8*)(dA + m * 128 + (kk2 ^ ((m & 7) << 4)));
            }
            #pragma unroll
            for (int cI = 0; cI < FN; ++cI) {
                int n = wx * 64 + cI * 16 + (lane & 15);
                bfr[cI] = *(const bf16x8*)(dB + n * 128 + (kk2 ^ ((n & 7) << 4)));
            }
            #pragma unroll
            for (int r = 0; r < FM; ++r)
                #pragma unroll
                for (int cI = 0; cI < FN; ++cI)
                    acc[r][cI] = __builtin_amdgcn_mfma_f32_16x16x32_bf16(
                        af[r], bfr[cI], acc[r][cI], 0, 0, 0);
        }
        __syncthreads();     // protect buffer before next stage
    }

    #pragma unroll
    for (int r = 0; r < FM; ++r) {
        #pragma unroll
        for (int j = 0; j < 4; ++j) {
            int m = m0 + wy * 64 + r * 16 + (lane >> 4) * 4 + j;
            #pragma unroll
            for (int cI = 0; cI < FN; ++cI) {
                int n = n0 + wx * 64 + cI * 16 + (lane & 15);
                Cb[(size_t)m * 512 + n] = (bf16)acc[r][cI][j];
            }
        }
    }
}

__global__ __launch_bounds__(256) void out_gemm_kernel(
    const bf16* __restrict__ A, const bf16* __restrict__ Bt,
    const float* __restrict__ bias, float* __restrict__ C)
{
    __shared__ char lds[48 * 1024];
    gemm_body<SD, LD, 64, 4, 1, 0, 1, 1, 0>(
        A, Bt, bias, C, nullptr, NN, 0, blockIdx.x, lds);
}

// ---------------------------------------------------------------------------
// Fused prep: [input GEMM (inline fp32 staging)] + [LDS-tiled coalesced
// transposes of W_msg, W_out] + [bucket-append edge grouping].
// ---------------------------------------------------------------------------
#define GIN_BLK  (2 * (NP / 128))            // 392
#define TMSG_BLK (ROUNDS * 32)               // 128
#define TOUT_BLK 4
#define APP_BLK  ((NE + 255) / 256)          // 1563
#define PREP_BLKS (GIN_BLK + TMSG_BLK + TOUT_BLK + APP_BLK)

__global__ __launch_bounds__(256) void prep_fused(
    const float* __restrict__ x, const float* __restrict__ W_in,
    const float* __restrict__ W_msg, const float* __restrict__ W_out,
    const float* __restrict__ b_in,
    const int* __restrict__ src, const int* __restrict__ dest,
    bf16* __restrict__ sb, bf16* __restrict__ Wb, bf16* __restrict__ Wot,
    int* __restrict__ cnt, int* __restrict__ bucket)
{
    __shared__ union {
        struct { bf16 As[128][72]; bf16 Bs[128][72]; } g;   // 36.9 KB
        float tr[64][68];                                    // 17.4 KB
    } sm;

    const int bid = blockIdx.x;
    const int tid = threadIdx.x;

    if (bid < GIN_BLK) {
        const int lane = tid & 63, w = tid >> 6;
        const int wy = w >> 1, wx = w & 1;
        const int bx = bid & 1, by = bid >> 1;
        const int m0 = by * 128, n0 = bx * 128;
        f32x4 acc[4][4] = {};

        for (int k0 = 0; k0 < FD; k0 += 64) {
            #pragma unroll
            for (int i = 0; i < 8; ++i) {            // A: x fp32 -> bf16 LDS
                int c = i * 256 + tid;
                int row = c >> 4, off = (c & 15) * 4;
                int gr = m0 + row;
                float4 v = (gr < NN)
                    ? *(const float4*)&x[(size_t)gr * FD + k0 + off]
                    : make_float4(0.f, 0.f, 0.f, 0.f);
                bf16x4 o = { (bf16)v.x, (bf16)v.y, (bf16)v.z, (bf16)v.w };
                *(bf16x4*)&sm.g.As[row][off] = o;
            }
            #pragma unroll
            for (int ps = 0; ps < 8; ++ps) {         // B: W_in [k][n] -> Bs[n][k]
                int kr = ps * 8 + (tid >> 5);
                int nof = (tid & 31) * 4;
                float4 v = *(const float4*)&W_in[(size_t)(k0 + kr) * SD + n0 + nof];
                sm.g.Bs[nof + 0][kr] = (bf16)v.x;
                sm.g.Bs[nof + 1][kr] = (bf16)v.y;
                sm.g.Bs[nof + 2][kr] = (bf16)v.z;
                sm.g.Bs[nof + 3][kr] = (bf16)v.w;
            }
            __syncthreads();
            #pragma unroll
            for (int ks = 0; ks < 2; ++ks) {
                const int kk = ks * 32 + (lane >> 4) * 8;
                bf16x8 af[4], bfr[4];
                #pragma unroll
                for (int r = 0; r < 4; ++r)
                    af[r] = *(const bf16x8*)&sm.g.As[wy * 64 + r * 16 + (lane & 15)][kk];
                #pragma unroll
                for (int cI = 0; cI < 4; ++cI)
                    bfr[cI] = *(const bf16x8*)&sm.g.Bs[wx * 64 + cI * 16 + (lane & 15)][kk];
                #pragma unroll
                for (int r = 0; r < 4; ++r)
                    #pragma unroll
                    for (int cI = 0; cI < 4; ++cI)
                        acc[r][cI] = __builtin_amdgcn_mfma_f32_16x16x32_bf16(
                            af[r], bfr[cI], acc[r][cI], 0, 0, 0);
            }
            __syncthreads();
        }
        #pragma unroll
        for (int r = 0; r < 4; ++r)
            #pragma unroll
            for (int j = 0; j < 4; ++j) {
                int m = m0 + wy * 64 + r * 16 + (lane >> 4) * 4 + j;
                #pragma unroll
                for (int cI = 0; cI < 4; ++cI) {
                    int n = n0 + wx * 64 + cI * 16 + (lane & 15);
                    float v = fmaxf(acc[r][cI][j] + b_in[n], 0.f);
                    sb[(size_t)m * SD + n] = (bf16)v;
                }
            }
        return;
    }

    int tb = bid - GIN_BLK;
    if (tb < TMSG_BLK + TOUT_BLK) {
        // ---- 64x64 LDS-tiled transpose, fp32 -> bf16 ----
        const float* srcp; bf16* dstp; int sld, dld;
        if (tb < TMSG_BLK) {
            int r = tb >> 5, t5 = tb & 31, kt = t5 >> 2, nt = t5 & 3;
            int half = kt >> 2;
            srcp = W_msg + (size_t)r * 2 * SD * SD + (kt * 64) * SD + nt * 64;
            sld  = SD;
            dstp = Wb + (size_t)r * 2 * SD * SD
                      + (size_t)(half * 256 + nt * 64) * SD + (kt & 3) * 64;
            dld  = SD;
        } else {
            int kt = tb - TMSG_BLK;
            srcp = W_out + (size_t)kt * 64 * LD;
            sld  = LD;
            dstp = Wot + kt * 64;
            dld  = SD;
        }
        #pragma unroll
        for (int ps = 0; ps < 4; ++ps) {
            int row = ps * 16 + (tid >> 4), c0 = (tid & 15) * 4;
            float4 v = *(const float4*)&srcp[(size_t)row * sld + c0];
            sm.tr[row][c0 + 0] = v.x; sm.tr[row][c0 + 1] = v.y;
            sm.tr[row][c0 + 2] = v.z; sm.tr[row][c0 + 3] = v.w;
        }
        __syncthreads();
        #pragma unroll
        for (int ps = 0; ps < 4; ++ps) {
            int j = ps * 16 + (tid >> 4), i0 = (tid & 15) * 4;
            bf16x4 o = { (bf16)sm.tr[i0 + 0][j], (bf16)sm.tr[i0 + 1][j],
                         (bf16)sm.tr[i0 + 2][j], (bf16)sm.tr[i0 + 3][j] };
            *(bf16x4*)&dstp[(size_t)j * dld + i0] = o;
        }
        return;
    }

    // ---- bucket-append edge grouping ----
    int e = (tb - TMSG_BLK - TOUT_BLK) * 256 + tid;
    if (e < NE) {
        int d = dest[e];
        int pos = atomicAdd(&cnt[d], 1);
        if (pos < CAP) bucket[(size_t)d * CAP + pos] = src[e];
    }
}

// ---------------------------------------------------------------------------
// Zero kernel for per-dest counters
// ---------------------------------------------------------------------------
__global__ __launch_bounds__(256) void zero_cnt(int* __restrict__ cnt)
{
    int i = blockIdx.x * 256 + threadIdx.x;
    if (i < NN) cnt[i] = 0;
}

// ---------------------------------------------------------------------------
// Gather: 4 waves/block, one dest node per wave.  Two edges per wave-iter:
// lanes 0-31 process edge 2i, lanes 32-63 edge 2i+1; each lane covers 8 cols
// (bf16x8, 16B loads).  Cross-half merge via __shfl_xor(,32) at the end.
// ---------------------------------------------------------------------------
__global__ __launch_bounds__(256) void gather_kernel(
    const bf16* __restrict__ PQ, const float* __restrict__ bias,
    const int* __restrict__ cnt, const int* __restrict__ bucket,
    bf16* __restrict__ sb)
{
    const int w  = threadIdx.x >> 6;
    const int t  = threadIdx.x & 63;
    const int h  = t >> 5;
    const int lc = t & 31;
    const int d  = blockIdx.x * 4 + w;
    if (d >= NN) return;
    const int deg = cnt[d];
    if (deg == 0) return;
    const int* row = bucket + (size_t)d * CAP;

    bf16x8 qv = *(const bf16x8*)&PQ[(size_t)d * 512 + 256 + lc * 8];
    float4 b0 = *(const float4*)&bias[lc * 8];
    float4 b1 = *(const float4*)&bias[lc * 8 + 4];
    float qb[8] = { (float)qv[0] + b0.x, (float)qv[1] + b0.y,
                    (float)qv[2] + b0.z, (float)qv[3] + b0.w,
                    (float)qv[4] + b1.x, (float)qv[5] + b1.y,
                    (float)qv[6] + b1.z, (float)qv[7] + b1.w };
    float s[8] = {};

    for (int c = 0; c < deg; c += 64) {
        int rem = min(64, deg - c);
        int et = (t < rem) ? row[c + t] : 0;
        int pairs = (rem + 1) >> 1;
        #pragma unroll 2
        for (int i = 0; i < pairs; ++i) {
            int idx = 2 * i + h;
            int sn = __shfl(et, idx);
            if (idx < rem) {
                bf16x8 p = *(const bf16x8*)&PQ[(size_t)sn * 512 + lc * 8];
                #pragma unroll
                for (int j = 0; j < 8; ++j)
                    s[j] += fmaxf((float)p[j] + qb[j], 0.f);
            }
        }
    }

    #pragma unroll
    for (int j = 0; j < 8; ++j) s[j] += __shfl_xor(s[j], 32);

    if (h == 0) {
        size_t o = (size_t)d * SD + lc * 8;
        bf16x8 old = *(const bf16x8*)&sb[o];
        bf16x8 nv;
        #pragma unroll
        for (int j = 0; j < 8; ++j) nv[j] = (bf16)((float)old[j] + s[j]);
        *(bf16x8*)&sb[o] = nv;
    }
}

extern "C" void kernel_launch(void* const* d_in, const int* in_sizes, int n_in,
                              void* d_out, int out_size, void* d_ws, size_t ws_size,
                              hipStream_t stream)
{
    const float* x      = (const float*)d_in[0];
    const int*   eidx   = (const int*)d_in[1];
    const float* W_in   = (const float*)d_in[3];
    const float* b_in   = (const float*)d_in[4];
    const float* W_msg  = (const float*)d_in[5];
    const float* b_msg  = (const float*)d_in[6];
    const float* W_out  = (const float*)d_in[7];
    const float* b_out  = (const float*)d_in[8];
    float* out = (float*)d_out;

    const int* src  = eidx;
    const int* dest = eidx + NE;

    // ---- workspace layout (~50 MB) ----
    char* p = (char*)d_ws;
    bf16*  sb    = (bf16*)p;            p += (size_t)NP * SD * 2;
    bf16*  PQb   = (bf16*)p;            p += (size_t)NP * 512 * 2;
    bf16*  Wb    = (bf16*)p;            p += (size_t)ROUNDS * 2 * SD * SD * 2;
    bf16*  Wot   = (bf16*)p;            p += (size_t)LD * SD * 2;
    int*   cnt   = (int*)p;             p += (size_t)NN * 4;
    int*   bucket= (int*)p;             p += (size_t)NN * CAP * 4;

    dim3 blk(256);

    // 1. zero per-dest counters
    zero_cnt<<<dim3((NN + 255) / 256), blk, 0, stream>>>(cnt);

    // 2. fused prep: input GEMM + weight transposes + bucket append
    prep_fused<<<dim3(PREP_BLKS), blk, 0, stream>>>(
        x, W_in, W_msg, W_out, b_in, src, dest, sb, Wb, Wot, cnt, bucket);

    // 3. message rounds: GEMM r (wide tile, one occupancy wave), gather r
    for (int r = 0; r < ROUNDS; ++r) {
        const bf16* Br = Wb + (size_t)r * 2 * SD * SD;
        msg_gemm_kernel<<<dim3(2, NP / 128), dim3(512), 0, stream>>>(sb, Br, PQb);
        gather_kernel<<<dim3((NN + 3) / 4), blk, 0, stream>>>(
            PQb, b_msg + (size_t)r * SD, cnt, bucket, sb);
    }

    // 4. output net
    out_gemm_kernel<<<dim3(NP / 128), blk, 0, stream>>>(sb, Wot, b_out, out);
}

// Round 14
// 219.837 us; speedup vs baseline: 15.1100x; 1.0285x over previous
//
#include <hip/hip_runtime.h>

#define NN 25000
#define NP 25088   // NN padded to multiple of 128
#define FD 128
#define SD 256
#define LD 64
#define NE 400000
#define ROUNDS 4
#define CAP 96     // bucket capacity per dest (Poisson(16); P(deg>96)~1e-50)

typedef __bf16 bf16;
typedef __bf16 bf16x4 __attribute__((ext_vector_type(4)));
typedef __bf16 bf16x8 __attribute__((ext_vector_type(8)));
typedef float  f32x4  __attribute__((ext_vector_type(4)));

// async global->LDS, 16B per lane; LDS dest = wave-uniform base + lane*16
#define GL16(g, l) __builtin_amdgcn_global_load_lds(                      \
    (const __attribute__((address_space(1))) void*)(g),                   \
    (__attribute__((address_space(3))) void*)(l), 16, 0, 0)

// ---------------------------------------------------------------------------
// bf16 MFMA GEMM body (round-6 proven, 4-wave): gload_lds + XOR swizzle +
// 2-phase double buffer.  Used by out_gemm.
// ---------------------------------------------------------------------------
template<int K_, int NTOT, int BN, int WM, int WN, int RELU, int BIAS,
         int WF32, int WBF>
__device__ __forceinline__ void gemm_body(
    const bf16* __restrict__ A, const bf16* __restrict__ Bt,
    const float* __restrict__ bias, float* __restrict__ C,
    bf16* __restrict__ Cb, int M, int bx, int by, char* lds)
{
    constexpr int BM = 128, BK = 64;
    constexpr int NT = K_ / BK;
    constexpr int FM = BM / WM / 16;
    constexpr int FN = BN / WN / 16;
    constexpr int ABYTES = BM * BK * 2;
    constexpr int BBYTES = BN * BK * 2;
    constexpr int BUF = ABYTES + BBYTES;
    constexpr int BCHW = (BN / 8) / 4;

    const int tid  = threadIdx.x;
    const int lane = tid & 63;
    const int w    = tid >> 6;
    const int wy   = w / WN;
    const int wx   = w % WN;
    const int m0   = by * BM;
    const int n0   = bx * BN;

    const int l8 = lane >> 3;
    const int bs = 16 * ((lane & 7) ^ l8);

    const char* Abase = (const char*)(A + (size_t)m0 * K_);
    const char* Bbase = (const char*)(Bt + (size_t)n0 * K_);

    f32x4 acc[FM][FN] = {};

#define STAGE(bufi, k0) do {                                              \
    char* dA = lds + (bufi) * BUF;                                        \
    char* dB = dA + ABYTES;                                               \
    _Pragma("unroll")                                                     \
    for (int i = 0; i < 4; ++i) {                                         \
        int c = w * 4 + i;                                                \
        GL16(Abase + (size_t)(c * 8 + l8) * (K_ * 2) + (k0) * 2 + bs,     \
             dA + c * 1024);                                              \
    }                                                                     \
    _Pragma("unroll")                                                     \
    for (int i = 0; i < BCHW; ++i) {                                      \
        int c = w * BCHW + i;                                             \
        GL16(Bbase + (size_t)(c * 8 + l8) * (K_ * 2) + (k0) * 2 + bs,     \
             dB + c * 1024);                                              \
    } } while (0)

    STAGE(0, 0);
    __syncthreads();

    for (int t = 0; t < NT; ++t) {
        if (t + 1 < NT) STAGE((t + 1) & 1, (t + 1) * BK);
        const char* Ab = lds + (t & 1) * BUF;
        const char* Bb = Ab + ABYTES;
        #pragma unroll
        for (int ks = 0; ks < 2; ++ks) {
            const int kk2 = ks * 64 + (lane >> 4) * 16;
            bf16x8 af[FM], bfr[FN];
            #pragma unroll
            for (int r = 0; r < FM; ++r) {
                int m = wy * (FM * 16) + r * 16 + (lane & 15);
                af[r] = *(const bf16x8*)(Ab + m * 128 + (kk2 ^ ((m & 7) << 4)));
            }
            #pragma unroll
            for (int cI = 0; cI < FN; ++cI) {
                int n = wx * (FN * 16) + cI * 16 + (lane & 15);
                bfr[cI] = *(const bf16x8*)(Bb + n * 128 + (kk2 ^ ((n & 7) << 4)));
            }
            #pragma unroll
            for (int r = 0; r < FM; ++r)
                #pragma unroll
                for (int cI = 0; cI < FN; ++cI)
                    acc[r][cI] = __builtin_amdgcn_mfma_f32_16x16x32_bf16(
                        af[r], bfr[cI], acc[r][cI], 0, 0, 0);
        }
        __syncthreads();
    }
#undef STAGE

    #pragma unroll
    for (int r = 0; r < FM; ++r) {
        #pragma unroll
        for (int j = 0; j < 4; ++j) {
            int m = m0 + wy * (FM * 16) + r * 16 + (lane >> 4) * 4 + j;
            if (m >= M) continue;
            #pragma unroll
            for (int cI = 0; cI < FN; ++cI) {
                int n = n0 + wx * (FN * 16) + cI * 16 + (lane & 15);
                float v = acc[r][cI][j];
                if (BIAS) v += bias[n];
                if (RELU) v = fmaxf(v, 0.f);
                if (WF32) C[(size_t)m * NTOT + n] = v;
                if (WBF)  Cb[(size_t)m * NTOT + n] = (bf16)v;
            }
        }
    }
}

// ---------------------------------------------------------------------------
// Msg GEMM: single-buffer, BN=256 wide tile, 8 waves (512 threads).
// Grid 2 x 196 = 392 blocks at 2 blocks/CU -> one occupancy wave.
// ---------------------------------------------------------------------------
__global__ __launch_bounds__(512, 4) void msg_gemm_kernel(
    const bf16* __restrict__ A, const bf16* __restrict__ Bt,
    bf16* __restrict__ Cb)
{
    constexpr int K_ = SD, BN = 256;
    constexpr int BM = 128, BK = 64;
    constexpr int NT = K_ / BK;          // 4
    constexpr int FM = 4, FN = 4;        // each wave: 64x64 output
    constexpr int ABYTES = BM * BK * 2;  // 16 KB
    __shared__ char lds[48 * 1024];      // A 16KB + B 32KB

    const int tid  = threadIdx.x;
    const int lane = tid & 63;
    const int w    = tid >> 6;           // 0..7
    const int wy   = w >> 2;             // 0..1
    const int wx   = w & 3;              // 0..3
    const int m0   = blockIdx.y * BM;
    const int n0   = blockIdx.x * BN;

    const int l8 = lane >> 3;
    const int bs = 16 * ((lane & 7) ^ l8);

    const char* Abase = (const char*)(A + (size_t)m0 * K_);
    const char* Bbase = (const char*)(Bt + (size_t)n0 * K_);
    char* dA = lds;
    char* dB = lds + ABYTES;

    f32x4 acc[FM][FN] = {};

    for (int t = 0; t < NT; ++t) {
        const int k0 = t * BK;
        #pragma unroll
        for (int i = 0; i < 2; ++i) {                // A: 16 chunks / 8 waves
            int c = w * 2 + i;
            GL16(Abase + (size_t)(c * 8 + l8) * (K_ * 2) + k0 * 2 + bs,
                 dA + c * 1024);
        }
        #pragma unroll
        for (int i = 0; i < 4; ++i) {                // B: 32 chunks / 8 waves
            int c = w * 4 + i;
            GL16(Bbase + (size_t)(c * 8 + l8) * (K_ * 2) + k0 * 2 + bs,
                 dB + c * 1024);
        }
        __syncthreads();

        #pragma unroll
        for (int ks = 0; ks < 2; ++ks) {
            const int kk2 = ks * 64 + (lane >> 4) * 16;
            bf16x8 af[FM], bfr[FN];
            #pragma unroll
            for (int r = 0; r < FM; ++r) {
                int m = wy * 64 + r * 16 + (lane & 15);
                af[r] = *(const bf16x8*)(dA + m * 128 + (kk2 ^ ((m & 7) << 4)));
            }
            #pragma unroll
            for (int cI = 0; cI < FN; ++cI) {
                int n = wx * 64 + cI * 16 + (lane & 15);
                bfr[cI] = *(const bf16x8*)(dB + n * 128 + (kk2 ^ ((n & 7) << 4)));
            }
            #pragma unroll
            for (int r = 0; r < FM; ++r)
                #pragma unroll
                for (int cI = 0; cI < FN; ++cI)
                    acc[r][cI] = __builtin_amdgcn_mfma_f32_16x16x32_bf16(
                        af[r], bfr[cI], acc[r][cI], 0, 0, 0);
        }
        __syncthreads();
    }

    #pragma unroll
    for (int r = 0; r < FM; ++r) {
        #pragma unroll
        for (int j = 0; j < 4; ++j) {
            int m = m0 + wy * 64 + r * 16 + (lane >> 4) * 4 + j;
            #pragma unroll
            for (int cI = 0; cI < FN; ++cI) {
                int n = n0 + wx * 64 + cI * 16 + (lane & 15);
                Cb[(size_t)m * 512 + n] = (bf16)acc[r][cI][j];
            }
        }
    }
}

__global__ __launch_bounds__(256) void out_gemm_kernel(
    const bf16* __restrict__ A, const bf16* __restrict__ Bt,
    const float* __restrict__ bias, float* __restrict__ C)
{
    __shared__ char lds[48 * 1024];
    gemm_body<SD, LD, 64, 4, 1, 0, 1, 1, 0>(
        A, Bt, bias, C, nullptr, NN, 0, blockIdx.x, lds);
}

// ---------------------------------------------------------------------------
// Fused prep: [input GEMM (inline fp32 staging)] + [LDS-tiled coalesced
// transposes of W_msg, W_out] + [bucket-append edge grouping].
// ---------------------------------------------------------------------------
#define GIN_BLK  (2 * (NP / 128))            // 392
#define TMSG_BLK (ROUNDS * 32)               // 128
#define TOUT_BLK 4
#define APP_BLK  ((NE + 255) / 256)          // 1563
#define PREP_BLKS (GIN_BLK + TMSG_BLK + TOUT_BLK + APP_BLK)

__global__ __launch_bounds__(256) void prep_fused(
    const float* __restrict__ x, const float* __restrict__ W_in,
    const float* __restrict__ W_msg, const float* __restrict__ W_out,
    const float* __restrict__ b_in,
    const int* __restrict__ src, const int* __restrict__ dest,
    bf16* __restrict__ sb, bf16* __restrict__ Wb, bf16* __restrict__ Wot,
    int* __restrict__ cnt, int* __restrict__ bucket)
{
    __shared__ union {
        struct { bf16 As[128][72]; bf16 Bs[128][72]; } g;   // 36.9 KB
        float tr[64][68];                                    // 17.4 KB
    } sm;

    const int bid = blockIdx.x;
    const int tid = threadIdx.x;

    if (bid < GIN_BLK) {
        const int lane = tid & 63, w = tid >> 6;
        const int wy = w >> 1, wx = w & 1;
        const int bx = bid & 1, by = bid >> 1;
        const int m0 = by * 128, n0 = bx * 128;
        f32x4 acc[4][4] = {};

        for (int k0 = 0; k0 < FD; k0 += 64) {
            #pragma unroll
            for (int i = 0; i < 8; ++i) {            // A: x fp32 -> bf16 LDS
                int c = i * 256 + tid;
                int row = c >> 4, off = (c & 15) * 4;
                int gr = m0 + row;
                float4 v = (gr < NN)
                    ? *(const float4*)&x[(size_t)gr * FD + k0 + off]
                    : make_float4(0.f, 0.f, 0.f, 0.f);
                bf16x4 o = { (bf16)v.x, (bf16)v.y, (bf16)v.z, (bf16)v.w };
                *(bf16x4*)&sm.g.As[row][off] = o;
            }
            #pragma unroll
            for (int ps = 0; ps < 8; ++ps) {         // B: W_in [k][n] -> Bs[n][k]
                int kr = ps * 8 + (tid >> 5);
                int nof = (tid & 31) * 4;
                float4 v = *(const float4*)&W_in[(size_t)(k0 + kr) * SD + n0 + nof];
                sm.g.Bs[nof + 0][kr] = (bf16)v.x;
                sm.g.Bs[nof + 1][kr] = (bf16)v.y;
                sm.g.Bs[nof + 2][kr] = (bf16)v.z;
                sm.g.Bs[nof + 3][kr] = (bf16)v.w;
            }
            __syncthreads();
            #pragma unroll
            for (int ks = 0; ks < 2; ++ks) {
                const int kk = ks * 32 + (lane >> 4) * 8;
                bf16x8 af[4], bfr[4];
                #pragma unroll
                for (int r = 0; r < 4; ++r)
                    af[r] = *(const bf16x8*)&sm.g.As[wy * 64 + r * 16 + (lane & 15)][kk];
                #pragma unroll
                for (int cI = 0; cI < 4; ++cI)
                    bfr[cI] = *(const bf16x8*)&sm.g.Bs[wx * 64 + cI * 16 + (lane & 15)][kk];
                #pragma unroll
                for (int r = 0; r < 4; ++r)
                    #pragma unroll
                    for (int cI = 0; cI < 4; ++cI)
                        acc[r][cI] = __builtin_amdgcn_mfma_f32_16x16x32_bf16(
                            af[r], bfr[cI], acc[r][cI], 0, 0, 0);
            }
            __syncthreads();
        }
        #pragma unroll
        for (int r = 0; r < 4; ++r)
            #pragma unroll
            for (int j = 0; j < 4; ++j) {
                int m = m0 + wy * 64 + r * 16 + (lane >> 4) * 4 + j;
                #pragma unroll
                for (int cI = 0; cI < 4; ++cI) {
                    int n = n0 + wx * 64 + cI * 16 + (lane & 15);
                    float v = fmaxf(acc[r][cI][j] + b_in[n], 0.f);
                    sb[(size_t)m * SD + n] = (bf16)v;
                }
            }
        return;
    }

    int tb = bid - GIN_BLK;
    if (tb < TMSG_BLK + TOUT_BLK) {
        // ---- 64x64 LDS-tiled transpose, fp32 -> bf16 ----
        const float* srcp; bf16* dstp; int sld, dld;
        if (tb < TMSG_BLK) {
            int r = tb >> 5, t5 = tb & 31, kt = t5 >> 2, nt = t5 & 3;
            int half = kt >> 2;
            srcp = W_msg + (size_t)r * 2 * SD * SD + (kt * 64) * SD + nt * 64;
            sld  = SD;
            dstp = Wb + (size_t)r * 2 * SD * SD
                      + (size_t)(half * 256 + nt * 64) * SD + (kt & 3) * 64;
            dld  = SD;
        } else {
            int kt = tb - TMSG_BLK;
            srcp = W_out + (size_t)kt * 64 * LD;
            sld  = LD;
            dstp = Wot + kt * 64;
            dld  = SD;
        }
        #pragma unroll
        for (int ps = 0; ps < 4; ++ps) {
            int row = ps * 16 + (tid >> 4), c0 = (tid & 15) * 4;
            float4 v = *(const float4*)&srcp[(size_t)row * sld + c0];
            sm.tr[row][c0 + 0] = v.x; sm.tr[row][c0 + 1] = v.y;
            sm.tr[row][c0 + 2] = v.z; sm.tr[row][c0 + 3] = v.w;
        }
        __syncthreads();
        #pragma unroll
        for (int ps = 0; ps < 4; ++ps) {
            int j = ps * 16 + (tid >> 4), i0 = (tid & 15) * 4;
            bf16x4 o = { (bf16)sm.tr[i0 + 0][j], (bf16)sm.tr[i0 + 1][j],
                         (bf16)sm.tr[i0 + 2][j], (bf16)sm.tr[i0 + 3][j] };
            *(bf16x4*)&dstp[(size_t)j * dld + i0] = o;
        }
        return;
    }

    // ---- bucket-append edge grouping ----
    int e = (tb - TMSG_BLK - TOUT_BLK) * 256 + tid;
    if (e < NE) {
        int d = dest[e];
        int pos = atomicAdd(&cnt[d], 1);
        if (pos < CAP) bucket[(size_t)d * CAP + pos] = src[e];
    }
}

// ---------------------------------------------------------------------------
// Zero kernel for per-dest counters
// ---------------------------------------------------------------------------
__global__ __launch_bounds__(256) void zero_cnt(int* __restrict__ cnt)
{
    int i = blockIdx.x * 256 + threadIdx.x;
    if (i < NN) cnt[i] = 0;
}

// ---------------------------------------------------------------------------
// Gather: 4 waves/block, one dest node per wave.  FOUR edges per wave-iter:
// lane-half h processes edges 4i+h and 4i+2+h -> 2 independent load chains
// per lane (deepened MLP vs round-13's 1).  Each lane covers 8 cols (bf16x8,
// 16B loads).  Cross-half merge via __shfl_xor(,32) at the end.
// ---------------------------------------------------------------------------
__global__ __launch_bounds__(256) void gather_kernel(
    const bf16* __restrict__ PQ, const float* __restrict__ bias,
    const int* __restrict__ cnt, const int* __restrict__ bucket,
    bf16* __restrict__ sb)
{
    const int w  = threadIdx.x >> 6;
    const int t  = threadIdx.x & 63;
    const int h  = t >> 5;
    const int lc = t & 31;
    const int d  = blockIdx.x * 4 + w;
    if (d >= NN) return;
    const int deg = min(cnt[d], CAP);
    if (deg == 0) return;
    const int* row = bucket + (size_t)d * CAP;

    bf16x8 qv = *(const bf16x8*)&PQ[(size_t)d * 512 + 256 + lc * 8];
    float4 b0 = *(const float4*)&bias[lc * 8];
    float4 b1 = *(const float4*)&bias[lc * 8 + 4];
    float qb[8] = { (float)qv[0] + b0.x, (float)qv[1] + b0.y,
                    (float)qv[2] + b0.z, (float)qv[3] + b0.w,
                    (float)qv[4] + b1.x, (float)qv[5] + b1.y,
                    (float)qv[6] + b1.z, (float)qv[7] + b1.w };
    float s[8] = {};

    for (int c = 0; c < deg; c += 64) {
        int rem = min(64, deg - c);
        int et = (t < rem) ? row[c + t] : 0;
        int quads = (rem + 3) >> 2;
        #pragma unroll 2
        for (int i = 0; i < quads; ++i) {
            int i0 = 4 * i + h;
            int i1 = 4 * i + 2 + h;
            int sn0 = __shfl(et, i0);
            int sn1 = __shfl(et, i1);
            // issue both independent loads before consuming either
            bf16x8 p0, p1;
            bool v0 = i0 < rem, v1 = i1 < rem;
            if (v0) p0 = *(const bf16x8*)&PQ[(size_t)sn0 * 512 + lc * 8];
            if (v1) p1 = *(const bf16x8*)&PQ[(size_t)sn1 * 512 + lc * 8];
            if (v0) {
                #pragma unroll
                for (int j = 0; j < 8; ++j)
                    s[j] += fmaxf((float)p0[j] + qb[j], 0.f);
            }
            if (v1) {
                #pragma unroll
                for (int j = 0; j < 8; ++j)
                    s[j] += fmaxf((float)p1[j] + qb[j], 0.f);
            }
        }
    }

    #pragma unroll
    for (int j = 0; j < 8; ++j) s[j] += __shfl_xor(s[j], 32);

    if (h == 0) {
        size_t o = (size_t)d * SD + lc * 8;
        bf16x8 old = *(const bf16x8*)&sb[o];
        bf16x8 nv;
        #pragma unroll
        for (int j = 0; j < 8; ++j) nv[j] = (bf16)((float)old[j] + s[j]);
        *(bf16x8*)&sb[o] = nv;
    }
}

extern "C" void kernel_launch(void* const* d_in, const int* in_sizes, int n_in,
                              void* d_out, int out_size, void* d_ws, size_t ws_size,
                              hipStream_t stream)
{
    const float* x      = (const float*)d_in[0];
    const int*   eidx   = (const int*)d_in[1];
    const float* W_in   = (const float*)d_in[3];
    const float* b_in   = (const float*)d_in[4];
    const float* W_msg  = (const float*)d_in[5];
    const float* b_msg  = (const float*)d_in[6];
    const float* W_out  = (const float*)d_in[7];
    const float* b_out  = (const float*)d_in[8];
    float* out = (float*)d_out;

    const int* src  = eidx;
    const int* dest = eidx + NE;

    // ---- workspace layout (~50 MB) ----
    char* p = (char*)d_ws;
    bf16*  sb    = (bf16*)p;            p += (size_t)NP * SD * 2;
    bf16*  PQb   = (bf16*)p;            p += (size_t)NP * 512 * 2;
    bf16*  Wb    = (bf16*)p;            p += (size_t)ROUNDS * 2 * SD * SD * 2;
    bf16*  Wot   = (bf16*)p;            p += (size_t)LD * SD * 2;
    int*   cnt   = (int*)p;             p += (size_t)NN * 4;
    int*   bucket= (int*)p;             p += (size_t)NN * CAP * 4;

    dim3 blk(256);

    // 1. zero per-dest counters
    zero_cnt<<<dim3((NN + 255) / 256), blk, 0, stream>>>(cnt);

    // 2. fused prep: input GEMM + weight transposes + bucket append
    prep_fused<<<dim3(PREP_BLKS), blk, 0, stream>>>(
        x, W_in, W_msg, W_out, b_in, src, dest, sb, Wb, Wot, cnt, bucket);

    // 3. message rounds: GEMM r (wide tile), gather r (deepened MLP)
    for (int r = 0; r < ROUNDS; ++r) {
        const bf16* Br = Wb + (size_t)r * 2 * SD * SD;
        msg_gemm_kernel<<<dim3(2, NP / 128), dim3(512), 0, stream>>>(sb, Br, PQb);
        gather_kernel<<<dim3((NN + 3) / 4), blk, 0, stream>>>(
            PQb, b_msg + (size_t)r * SD, cnt, bucket, sb);
    }

    // 4. output net
    out_gemm_kernel<<<dim3(NP / 128), blk, 0, stream>>>(sb, Wot, b_out, out);
}